// Round 5
// baseline (658.937 us; speedup 1.0000x reference)
//
#include <hip/hip_runtime.h>
#include <cmath>

#define IMG_H 256
#define IMG_W 256
#define N_B   16
#define N_C   32
#define HALO  10
#define TY    32                 // output rows per block
#define LROWS (TY + 2*HALO)      // 52
#define LPITCH 276               // 276 % 32 == 20: wave's two rows on complementary bank halves

typedef float f32x4 __attribute__((ext_vector_type(4)));
typedef float f32x2 __attribute__((ext_vector_type(2)));

// element i of a bank of f32x4 quads
#define EL(arr, i) arr[(i) >> 2][(i) & 3]

// Packed FMA: acc(2xf32) += w2(sgpr pair, duplicated weight) * s2(vgpr pair).
// All operands are genuine aligned 64-bit pairs -> no op_sel needed.
#define PKFMA(acc, w2, s2) \
    asm("v_pk_fma_f32 %0, %1, %2, %0" : "+v"(acc) : "s"(w2), "v"(s2))

// ---------------------------------------------------------------------------
// Kernel 1: build the 8 (center,surround) normalized 21x21 kernels.
// Tables store DUPLICATED weights: wtC[t][i] = (wc,wc), wtS[t][i] = (ws,ws),
// so a uniform s_load_dwordx2 gives a broadcast SGPR pair for v_pk_fma_f32.
// ---------------------------------------------------------------------------
__global__ void prep_kernel(float* __restrict__ wtC, float* __restrict__ wtS,
                            unsigned* __restrict__ mnb, unsigned* __restrict__ mxb) {
    int t = blockIdx.x;      // theta index 0..7
    int i = threadIdx.x;     // 0..511
    __shared__ float red0[512];
    __shared__ float red1[512];
    float wc = 0.f, wsv = 0.f;
    if (i < 441) {
        int ky = i / 21, kx = i % 21;
        float theta = (float)((double)t * 3.14159265358979323846 / 8.0);
        float ct = cosf(theta), st = sinf(theta);
        float xi = (float)(ky - 10), yj = (float)(kx - 10);   // meshgrid 'ij'
        float xr =  xi*ct + yj*st;
        float yr = -xi*st + yj*ct;
        const float sx  = 3.65f,      sy  = 3.65f/8.0f;
        const float sx3 = 3.65f*3.0f, sy3 = (3.65f/8.0f)*3.0f;
        wc  = expf(-0.5f*(xr*xr/(sx*sx)   + yr*yr/(sy*sy)));
        wsv = expf(-0.5f*(xr*xr/(sx3*sx3) + yr*yr/(sy3*sy3)));
    }
    red0[i] = wc; red1[i] = wsv;
    __syncthreads();
    for (int s = 256; s > 0; s >>= 1) {
        if (i < s) { red0[i] += red0[i+s]; red1[i] += red1[i+s]; }
        __syncthreads();
    }
    if (i < 441) {
        float c = wc  / red0[0];
        float s = wsv / red1[0];
        wtC[(t*441 + i)*2 + 0] = c;  wtC[(t*441 + i)*2 + 1] = c;
        wtS[(t*441 + i)*2 + 0] = s;  wtS[(t*441 + i)*2 + 1] = s;
    }
    if (t == 0 && i < N_C) { mnb[i] = 0x7f800000u; mxb[i] = 0u; }  // +inf / 0
}

// ---------------------------------------------------------------------------
// Kernel 2: per-channel global min/max of lstd (3x3 count_include_pad pool).
// Streaming column kernel with 3-row register ring; ~1.1x read of input.
// ---------------------------------------------------------------------------
#define LOADROW(yy, V, Q) {                                              \
    f32x4 m = {0.f,0.f,0.f,0.f};                                         \
    if ((unsigned)(yy) < IMG_H) m = *(const f32x4*)(img + (yy)*IMG_W + cx); \
    float lf = __shfl_up(m[3], 1);                                       \
    float rt = __shfl_down(m[0], 1);                                     \
    if (l == 0)  lf = 0.f;                                               \
    if (l == 63) rt = 0.f;                                               \
    V[0]=lf; V[1]=m[0]; V[2]=m[1]; V[3]=m[2]; V[4]=m[3]; V[5]=rt;        \
    Q[0]=lf*lf; Q[1]=m[0]*m[0]; Q[2]=m[1]*m[1];                          \
    Q[3]=m[2]*m[2]; Q[4]=m[3]*m[3]; Q[5]=rt*rt;                          \
}

__global__ __launch_bounds__(256) void lstd_minmax_kernel(
    const float* __restrict__ x, unsigned* __restrict__ mnb, unsigned* __restrict__ mxb) {
    const int plane = blockIdx.y;                 // 0..511
    const int c     = plane & (N_C - 1);
    const float* __restrict__ img = x + (size_t)plane * (IMG_H*IMG_W);
    const int w  = threadIdx.x >> 6, l = threadIdx.x & 63;
    const int y0 = blockIdx.x * 64 + w * 16;      // 16 output rows per thread
    const int cx = l * 4;

    float v[3][6], q[3][6];
    LOADROW(y0-1, v[0], q[0]);
    LOADROW(y0,   v[1], q[1]);

    float lmin = 1e30f, lmax = -1e30f;
    #pragma unroll
    for (int i = 0; i < 16; ++i) {
        LOADROW(y0+i+1, v[(i+2)%3], q[(i+2)%3]);
        const float* a  = v[i%3];  const float* b  = v[(i+1)%3];  const float* e  = v[(i+2)%3];
        const float* qa = q[i%3];  const float* qb = q[(i+1)%3];  const float* qe = q[(i+2)%3];
        float s1[6], s2[6];
        #pragma unroll
        for (int j = 0; j < 6; ++j) { s1[j] = a[j]+b[j]+e[j]; s2[j] = qa[j]+qb[j]+qe[j]; }
        #pragma unroll
        for (int o = 0; o < 4; ++o) {
            float t1 = s1[o] + s1[o+1] + s1[o+2];
            float t2 = s2[o] + s2[o+1] + s2[o+2];
            float avg = t1 * (1.0f/9.0f), avq = t2 * (1.0f/9.0f);
            float lv = sqrtf(fmaxf(avq - avg*avg, 1e-6f));
            lmin = fminf(lmin, lv); lmax = fmaxf(lmax, lv);
        }
    }
    #pragma unroll
    for (int off = 32; off >= 1; off >>= 1) {
        lmin = fminf(lmin, __shfl_xor(lmin, off));
        lmax = fmaxf(lmax, __shfl_xor(lmax, off));
    }
    __shared__ float smin[4], smax[4];
    if (l == 0) { smin[w] = lmin; smax[w] = lmax; }
    __syncthreads();
    if (threadIdx.x == 0) {
        float m0 = fminf(fminf(smin[0], smin[1]), fminf(smin[2], smin[3]));
        float m1 = fmaxf(fmaxf(smax[0], smax[1]), fmaxf(smax[2], smax[3]));
        atomicMin((int*)&mnb[c], __float_as_int(m0));
        atomicMax((int*)&mxb[c], __float_as_int(m1));
    }
}

// ---------------------------------------------------------------------------
// Kernel 3: main fused conv kernel.
// 8 outputs/thread (32 lanes/row, wave spans 2 rows). Inner loop is explicit
// v_pk_fma_f32 inline asm: accumulators are f32x2 pairs, symmetric sums s are
// built pairwise into f32x2 by scalar adds, weights come as duplicated SGPR
// pairs from the table (s_load_dwordx2, scalar pipe = free). Per tap-pair:
// 8 v_add_f32 + 8 v_pk_fma_f32 = 16 VALU covering 32 MACs.
// asm "+v" pins on the window quads keep the loads as ds_read_b128.
// ---------------------------------------------------------------------------
__global__ __launch_bounds__(512, 4) void texsup_kernel(
    const float* __restrict__ x,
    const float* __restrict__ wtC, const float* __restrict__ wtS,
    const unsigned* __restrict__ mnb, const unsigned* __restrict__ mxb,
    float* __restrict__ out)
{
    __shared__ float tile[LROWS][LPITCH];
    const int plane = blockIdx.z;          // 0..511
    const int b = plane >> 5, c = plane & 31;
    const float* __restrict__ img = x + (size_t)plane * (IMG_H*IMG_W);
    const int by0 = blockIdx.y * TY;
    const int tid = threadIdx.x;
    const int wid = tid >> 6, lane = tid & 63;
    const int ox4 = lane * 4;

    // stage: tile row r <-> img row by0 + r - 10; tile col t <-> img col t - 10
    for (int r = wid; r < LROWS; r += 8) {
        int gy = by0 + r - HALO;
        f32x4 vv = {0.f, 0.f, 0.f, 0.f};
        if ((unsigned)gy < IMG_H) vv = *(const f32x4*)(img + gy*IMG_W + ox4);
        *(f32x4*)&tile[r][HALO + ox4] = vv;
        if (lane < 10)       tile[r][lane]       = 0.f;    // cols 0..9
        else if (lane < 20)  tile[r][lane + 256] = 0.f;    // cols 266..275
    }
    __syncthreads();

    const float* __restrict__ wCbase = wtC + (size_t)(b & 7) * (441*2);
    const float* __restrict__ wSbase = wtS + (size_t)(b & 7) * (441*2);
    const float mnv = __uint_as_float(mnb[c]);
    const float mxv = __uint_as_float(mxb[c]);
    const float inv = 1.0f / (mxv - mnv + 1e-8f);

    const int half = lane >> 5;           // which of the wave's 2 rows
    const int col0 = (lane & 31) * 8;     // tile col of first output

    #pragma unroll 1
    for (int p = 0; p < 2; ++p) {
        const int wy = (wid << 2) + (p << 1) + half;   // output row in tile, 0..31

        f32x2 aC[4] = {{0.f,0.f},{0.f,0.f},{0.f,0.f},{0.f,0.f}};
        f32x2 aS[4] = {{0.f,0.f},{0.f,0.f},{0.f,0.f},{0.f,0.f}};

        // symmetric row pairs (ky, 20-ky), ky = 0..9
        #pragma unroll 1
        for (int kyp = 0; kyp < 10; ++kyp) {
            const float* rA = &tile[wy + kyp][col0];
            const float* rB = &tile[wy + 20 - kyp][col0];
            f32x4 A[7], B[7];
            #pragma unroll
            for (int qd = 0; qd < 7; ++qd) {
                A[qd] = *(const f32x4*)(rA + 4*qd);
                B[qd] = *(const f32x4*)(rB + 4*qd);
            }
            #pragma unroll
            for (int qd = 0; qd < 7; ++qd) {
                asm volatile("" : "+v"(A[qd]));
                asm volatile("" : "+v"(B[qd]));
            }
            const float* wC = wCbase + kyp*42;
            const float* wS = wSbase + kyp*42;
            #pragma unroll
            for (int kx = 0; kx < 21; ++kx) {
                const f32x2 wcc = *(const f32x2*)(wC + 2*kx);
                const f32x2 wss = *(const f32x2*)(wS + 2*kx);
                #pragma unroll
                for (int pr = 0; pr < 4; ++pr) {
                    f32x2 s2;
                    s2[0] = EL(A, kx + 2*pr)     + EL(B, 20 - kx + 2*pr);
                    s2[1] = EL(A, kx + 2*pr + 1) + EL(B, 20 - kx + 2*pr + 1);
                    PKFMA(aC[pr], wcc, s2);
                    PKFMA(aS[pr], wss, s2);
                }
            }
        }
        // middle row ky = 10
        {
            const float* rM = &tile[wy + 10][col0];
            f32x4 M[7];
            #pragma unroll
            for (int qd = 0; qd < 7; ++qd) M[qd] = *(const f32x4*)(rM + 4*qd);
            #pragma unroll
            for (int qd = 0; qd < 7; ++qd) asm volatile("" : "+v"(M[qd]));
            const float* wC = wCbase + 210*2;
            const float* wS = wSbase + 210*2;
            #pragma unroll
            for (int kx = 0; kx < 10; ++kx) {
                const f32x2 wcc = *(const f32x2*)(wC + 2*kx);
                const f32x2 wss = *(const f32x2*)(wS + 2*kx);
                #pragma unroll
                for (int pr = 0; pr < 4; ++pr) {
                    f32x2 s2;
                    s2[0] = EL(M, kx + 2*pr)     + EL(M, 20 - kx + 2*pr);
                    s2[1] = EL(M, kx + 2*pr + 1) + EL(M, 20 - kx + 2*pr + 1);
                    PKFMA(aC[pr], wcc, s2);
                    PKFMA(aS[pr], wss, s2);
                }
            }
            // lone center tap (ky=10, kx=10): acc += w220 * M[10+o]
            const f32x2 wcc = *(const f32x2*)(wCbase + 220*2);
            const f32x2 wss = *(const f32x2*)(wSbase + 220*2);
            #pragma unroll
            for (int pr = 0; pr < 4; ++pr) {
                f32x2 m2;
                m2[0] = EL(M, 10 + 2*pr);
                m2[1] = EL(M, 11 + 2*pr);
                PKFMA(aC[pr], wcc, m2);
                PKFMA(aS[pr], wss, m2);
            }
        }

        // epilogue: local std from tile (zeros outside image == count_include_pad)
        float d1[10], d2[10];
        #pragma unroll
        for (int j = 0; j < 10; ++j) { d1[j] = 0.f; d2[j] = 0.f; }
        #pragma unroll
        for (int dy = -1; dy <= 1; ++dy) {
            const float* rw = &tile[wy + 10 + dy][col0 + 8];
            f32x4 u0 = *(const f32x4*)(rw);
            f32x4 u1 = *(const f32x4*)(rw + 4);
            f32x4 u2 = *(const f32x4*)(rw + 8);
            float vv[10] = {u0[1],u0[2],u0[3],u1[0],u1[1],u1[2],u1[3],u2[0],u2[1],u2[2]};
            #pragma unroll
            for (int j = 0; j < 10; ++j) { d1[j] += vv[j]; d2[j] += vv[j]*vv[j]; }
        }
        float res[8];
        #pragma unroll
        for (int o = 0; o < 8; ++o) {
            float t1 = d1[o] + d1[o+1] + d1[o+2];
            float t2 = d2[o] + d2[o+1] + d2[o+2];
            float avg = t1 * (1.0f/9.0f), avq = t2 * (1.0f/9.0f);
            float lv = sqrtf(fmaxf(avq - avg*avg, 1e-6f));
            lv = (lv - mnv) * inv;
            float cc = aC[o>>1][o&1];
            float ss = aS[o>>1][o&1];
            res[o] = fmaxf(cc - lv * ss, 0.0f);
        }
        float* op = out + (size_t)plane*(IMG_H*IMG_W) + (size_t)(by0+wy)*IMG_W + col0;
        *(f32x4*)(op)     = (f32x4){res[0], res[1], res[2], res[3]};
        *(f32x4*)(op + 4) = (f32x4){res[4], res[5], res[6], res[7]};
    }
}

// ---------------------------------------------------------------------------
extern "C" void kernel_launch(void* const* d_in, const int* in_sizes, int n_in,
                              void* d_out, int out_size, void* d_ws, size_t ws_size,
                              hipStream_t stream) {
    const float* x = (const float*)d_in[0];
    float* out = (float*)d_out;

    float*    wtC = (float*)d_ws;                        // 8*441*2 f32 = 28224 B
    float*    wtS = wtC + 8*441*2;                       // 28224 B
    unsigned* mnb = (unsigned*)(wtS + 8*441*2);
    unsigned* mxb = mnb + N_C;

    hipLaunchKernelGGL(prep_kernel, dim3(8), dim3(512), 0, stream, wtC, wtS, mnb, mxb);
    hipLaunchKernelGGL(lstd_minmax_kernel, dim3(4, N_B*N_C), dim3(256), 0, stream,
                       x, mnb, mxb);
    hipLaunchKernelGGL(texsup_kernel, dim3(1, IMG_H/TY, N_B*N_C), dim3(512), 0, stream,
                       x, wtC, wtS, mnb, mxb, out);
}

// Round 6
// 654.449 us; speedup vs baseline: 1.0069x; 1.0069x over previous
//
#include <hip/hip_runtime.h>
#include <cmath>

#define IMG_H 256
#define IMG_W 256
#define N_B   16
#define N_C   32
#define HALO  10
#define TY    32                 // output rows per block
#define LROWS (TY + 2*HALO)      // 52
#define LPITCH 276               // 276 % 32 == 20: wave's two rows on complementary bank halves

typedef float f32x4 __attribute__((ext_vector_type(4)));
typedef float f32x2 __attribute__((ext_vector_type(2)));

// element i of a bank of f32x4 quads
#define EL(arr, i) arr[(i) >> 2][(i) & 3]

// acc(f32x2 = (C,S)) += (wc,ws) * broadcast(s).
// w2 = SGPR pair (wc,ws); s enters as lo of an undef-hi VGPR pair; op_sel_hi[1]=0
// makes BOTH result lanes read src1.lo -> the add's dst register is totally
// unconstrained: no pair-alignment marshaling anywhere.
#define PKFMA_CS(acc, w2, sval) do {                                      \
    f32x2 _vv; _vv[0] = (sval);                                           \
    asm("v_pk_fma_f32 %0, %1, %2, %0 op_sel:[0,0,0] op_sel_hi:[1,0,1]"    \
        : "+v"(acc) : "s"(w2), "v"(_vv));                                 \
} while (0)

// ---------------------------------------------------------------------------
// Kernel 1: build the 8 (center,surround) normalized 21x21 kernels.
// wtab layout: [theta][ky*21+kx][2] = (wc, ws) interleaved -> one s_load_dwordx2
// gives the (wc,ws) SGPR pair for PKFMA_CS.
// ---------------------------------------------------------------------------
__global__ void prep_kernel(float* __restrict__ wtab,
                            unsigned* __restrict__ mnb, unsigned* __restrict__ mxb) {
    int t = blockIdx.x;      // theta index 0..7
    int i = threadIdx.x;     // 0..511
    __shared__ float red0[512];
    __shared__ float red1[512];
    float wc = 0.f, wsv = 0.f;
    if (i < 441) {
        int ky = i / 21, kx = i % 21;
        float theta = (float)((double)t * 3.14159265358979323846 / 8.0);
        float ct = cosf(theta), st = sinf(theta);
        float xi = (float)(ky - 10), yj = (float)(kx - 10);   // meshgrid 'ij'
        float xr =  xi*ct + yj*st;
        float yr = -xi*st + yj*ct;
        const float sx  = 3.65f,      sy  = 3.65f/8.0f;
        const float sx3 = 3.65f*3.0f, sy3 = (3.65f/8.0f)*3.0f;
        wc  = expf(-0.5f*(xr*xr/(sx*sx)   + yr*yr/(sy*sy)));
        wsv = expf(-0.5f*(xr*xr/(sx3*sx3) + yr*yr/(sy3*sy3)));
    }
    red0[i] = wc; red1[i] = wsv;
    __syncthreads();
    for (int s = 256; s > 0; s >>= 1) {
        if (i < s) { red0[i] += red0[i+s]; red1[i] += red1[i+s]; }
        __syncthreads();
    }
    if (i < 441) {
        wtab[(t*441 + i)*2 + 0] = wc  / red0[0];
        wtab[(t*441 + i)*2 + 1] = wsv / red1[0];
    }
    if (t == 0 && i < N_C) { mnb[i] = 0x7f800000u; mxb[i] = 0u; }  // +inf / 0
}

// ---------------------------------------------------------------------------
// Kernel 2: per-channel global min/max of lstd (3x3 count_include_pad pool).
// Streaming column kernel with 3-row register ring; ~1.1x read of input.
// ---------------------------------------------------------------------------
#define LOADROW(yy, V, Q) {                                              \
    f32x4 m = {0.f,0.f,0.f,0.f};                                         \
    if ((unsigned)(yy) < IMG_H) m = *(const f32x4*)(img + (yy)*IMG_W + cx); \
    float lf = __shfl_up(m[3], 1);                                       \
    float rt = __shfl_down(m[0], 1);                                     \
    if (l == 0)  lf = 0.f;                                               \
    if (l == 63) rt = 0.f;                                               \
    V[0]=lf; V[1]=m[0]; V[2]=m[1]; V[3]=m[2]; V[4]=m[3]; V[5]=rt;        \
    Q[0]=lf*lf; Q[1]=m[0]*m[0]; Q[2]=m[1]*m[1];                          \
    Q[3]=m[2]*m[2]; Q[4]=m[3]*m[3]; Q[5]=rt*rt;                          \
}

__global__ __launch_bounds__(256) void lstd_minmax_kernel(
    const float* __restrict__ x, unsigned* __restrict__ mnb, unsigned* __restrict__ mxb) {
    const int plane = blockIdx.y;                 // 0..511
    const int c     = plane & (N_C - 1);
    const float* __restrict__ img = x + (size_t)plane * (IMG_H*IMG_W);
    const int w  = threadIdx.x >> 6, l = threadIdx.x & 63;
    const int y0 = blockIdx.x * 64 + w * 16;      // 16 output rows per thread
    const int cx = l * 4;

    float v[3][6], q[3][6];
    LOADROW(y0-1, v[0], q[0]);
    LOADROW(y0,   v[1], q[1]);

    float lmin = 1e30f, lmax = -1e30f;
    #pragma unroll
    for (int i = 0; i < 16; ++i) {
        LOADROW(y0+i+1, v[(i+2)%3], q[(i+2)%3]);
        const float* a  = v[i%3];  const float* b  = v[(i+1)%3];  const float* e  = v[(i+2)%3];
        const float* qa = q[i%3];  const float* qb = q[(i+1)%3];  const float* qe = q[(i+2)%3];
        float s1[6], s2[6];
        #pragma unroll
        for (int j = 0; j < 6; ++j) { s1[j] = a[j]+b[j]+e[j]; s2[j] = qa[j]+qb[j]+qe[j]; }
        #pragma unroll
        for (int o = 0; o < 4; ++o) {
            float t1 = s1[o] + s1[o+1] + s1[o+2];
            float t2 = s2[o] + s2[o+1] + s2[o+2];
            float avg = t1 * (1.0f/9.0f), avq = t2 * (1.0f/9.0f);
            float lv = sqrtf(fmaxf(avq - avg*avg, 1e-6f));
            lmin = fminf(lmin, lv); lmax = fmaxf(lmax, lv);
        }
    }
    #pragma unroll
    for (int off = 32; off >= 1; off >>= 1) {
        lmin = fminf(lmin, __shfl_xor(lmin, off));
        lmax = fmaxf(lmax, __shfl_xor(lmax, off));
    }
    __shared__ float smin[4], smax[4];
    if (l == 0) { smin[w] = lmin; smax[w] = lmax; }
    __syncthreads();
    if (threadIdx.x == 0) {
        float m0 = fminf(fminf(smin[0], smin[1]), fminf(smin[2], smin[3]));
        float m1 = fmaxf(fmaxf(smax[0], smax[1]), fmaxf(smax[2], smax[3]));
        atomicMin((int*)&mnb[c], __float_as_int(m0));
        atomicMax((int*)&mxb[c], __float_as_int(m1));
    }
}

// ---------------------------------------------------------------------------
// Kernel 3: main fused conv kernel.
// 8 outputs/thread (32 lanes/row, wave spans 2 rows). acc[o] packs the two
// convs (C,S) in one f32x2; each tap-pair per output = 1 v_add (unconstrained
// dst) + 1 v_pk_fma_f32 with op_sel broadcast = 2 insts / 4 MAC, zero
// register-pair marshaling. amdgpu_waves_per_eu(4,4): LDS caps us at
// 2 blocks/CU anyway, so let the compiler use the full 128-VGPR budget and
// keep the 14 window quads resident.
// ---------------------------------------------------------------------------
__global__ __launch_bounds__(512)
__attribute__((amdgpu_waves_per_eu(4, 4)))
void texsup_kernel(
    const float* __restrict__ x, const float* __restrict__ wtab,
    const unsigned* __restrict__ mnb, const unsigned* __restrict__ mxb,
    float* __restrict__ out)
{
    __shared__ float tile[LROWS][LPITCH];
    const int plane = blockIdx.z;          // 0..511
    const int b = plane >> 5, c = plane & 31;
    const float* __restrict__ img = x + (size_t)plane * (IMG_H*IMG_W);
    const int by0 = blockIdx.y * TY;
    const int tid = threadIdx.x;
    const int wid = tid >> 6, lane = tid & 63;
    const int ox4 = lane * 4;

    // stage: tile row r <-> img row by0 + r - 10; tile col t <-> img col t - 10
    for (int r = wid; r < LROWS; r += 8) {
        int gy = by0 + r - HALO;
        f32x4 vv = {0.f, 0.f, 0.f, 0.f};
        if ((unsigned)gy < IMG_H) vv = *(const f32x4*)(img + gy*IMG_W + ox4);
        *(f32x4*)&tile[r][HALO + ox4] = vv;
        if (lane < 10)       tile[r][lane]       = 0.f;    // cols 0..9
        else if (lane < 20)  tile[r][lane + 256] = 0.f;    // cols 266..275
    }
    __syncthreads();

    const float* __restrict__ wbase = wtab + (size_t)(b & 7) * (441*2);
    const float mnv = __uint_as_float(mnb[c]);
    const float mxv = __uint_as_float(mxb[c]);
    const float inv = 1.0f / (mxv - mnv + 1e-8f);

    const int half = lane >> 5;           // which of the wave's 2 rows
    const int col0 = (lane & 31) * 8;     // tile col of first output

    #pragma unroll 1
    for (int p = 0; p < 2; ++p) {
        const int wy = (wid << 2) + (p << 1) + half;   // output row in tile, 0..31

        f32x2 acc[8];
        #pragma unroll
        for (int o = 0; o < 8; ++o) acc[o] = (f32x2){0.f, 0.f};

        // symmetric row pairs (ky, 20-ky), ky = 0..9
        #pragma unroll 1
        for (int kyp = 0; kyp < 10; ++kyp) {
            const float* rA = &tile[wy + kyp][col0];
            const float* rB = &tile[wy + 20 - kyp][col0];
            f32x4 A[7], B[7];
            #pragma unroll
            for (int qd = 0; qd < 7; ++qd) {
                A[qd] = *(const f32x4*)(rA + 4*qd);
                B[qd] = *(const f32x4*)(rB + 4*qd);
            }
            #pragma unroll
            for (int qd = 0; qd < 7; ++qd) {
                asm volatile("" : "+v"(A[qd]));
                asm volatile("" : "+v"(B[qd]));
            }
            const float* w = wbase + kyp*42;
            #pragma unroll
            for (int kx = 0; kx < 21; ++kx) {
                const f32x2 w2 = *(const f32x2*)(w + 2*kx);
                #pragma unroll
                for (int o = 0; o < 8; ++o) {
                    float s = EL(A, kx + o) + EL(B, 20 - kx + o);
                    PKFMA_CS(acc[o], w2, s);
                }
            }
        }
        // middle row ky = 10
        {
            const float* rM = &tile[wy + 10][col0];
            f32x4 M[7];
            #pragma unroll
            for (int qd = 0; qd < 7; ++qd) M[qd] = *(const f32x4*)(rM + 4*qd);
            #pragma unroll
            for (int qd = 0; qd < 7; ++qd) asm volatile("" : "+v"(M[qd]));
            const float* w = wbase + 210*2;
            #pragma unroll
            for (int kx = 0; kx < 10; ++kx) {
                const f32x2 w2 = *(const f32x2*)(w + 2*kx);
                #pragma unroll
                for (int o = 0; o < 8; ++o) {
                    float s = EL(M, kx + o) + EL(M, 20 - kx + o);
                    PKFMA_CS(acc[o], w2, s);
                }
            }
            // lone center tap (ky=10, kx=10)
            const f32x2 w2 = *(const f32x2*)(wbase + 220*2);
            #pragma unroll
            for (int o = 0; o < 8; ++o) {
                float s = EL(M, 10 + o);
                PKFMA_CS(acc[o], w2, s);
            }
        }

        // epilogue: local std from tile (zeros outside image == count_include_pad)
        float d1[10], d2[10];
        #pragma unroll
        for (int j = 0; j < 10; ++j) { d1[j] = 0.f; d2[j] = 0.f; }
        #pragma unroll
        for (int dy = -1; dy <= 1; ++dy) {
            const float* rw = &tile[wy + 10 + dy][col0 + 8];
            f32x4 u0 = *(const f32x4*)(rw);
            f32x4 u1 = *(const f32x4*)(rw + 4);
            f32x4 u2 = *(const f32x4*)(rw + 8);
            float vv[10] = {u0[1],u0[2],u0[3],u1[0],u1[1],u1[2],u1[3],u2[0],u2[1],u2[2]};
            #pragma unroll
            for (int j = 0; j < 10; ++j) { d1[j] += vv[j]; d2[j] += vv[j]*vv[j]; }
        }
        float res[8];
        #pragma unroll
        for (int o = 0; o < 8; ++o) {
            float t1 = d1[o] + d1[o+1] + d1[o+2];
            float t2 = d2[o] + d2[o+1] + d2[o+2];
            float avg = t1 * (1.0f/9.0f), avq = t2 * (1.0f/9.0f);
            float lv = sqrtf(fmaxf(avq - avg*avg, 1e-6f));
            lv = (lv - mnv) * inv;
            res[o] = fmaxf(acc[o][0] - lv * acc[o][1], 0.0f);
        }
        float* op = out + (size_t)plane*(IMG_H*IMG_W) + (size_t)(by0+wy)*IMG_W + col0;
        *(f32x4*)(op)     = (f32x4){res[0], res[1], res[2], res[3]};
        *(f32x4*)(op + 4) = (f32x4){res[4], res[5], res[6], res[7]};
    }
}

// ---------------------------------------------------------------------------
extern "C" void kernel_launch(void* const* d_in, const int* in_sizes, int n_in,
                              void* d_out, int out_size, void* d_ws, size_t ws_size,
                              hipStream_t stream) {
    const float* x = (const float*)d_in[0];
    float* out = (float*)d_out;

    float*    wtab = (float*)d_ws;                       // 8*441*2 f32 = 28224 B
    unsigned* mnb  = (unsigned*)(wtab + 8*441*2);
    unsigned* mxb  = mnb + N_C;

    hipLaunchKernelGGL(prep_kernel, dim3(8), dim3(512), 0, stream, wtab, mnb, mxb);
    hipLaunchKernelGGL(lstd_minmax_kernel, dim3(4, N_B*N_C), dim3(256), 0, stream,
                       x, mnb, mxb);
    hipLaunchKernelGGL(texsup_kernel, dim3(1, IMG_H/TY, N_B*N_C), dim3(512), 0, stream,
                       x, wtab, mnb, mxb, out);
}